// Round 1
// baseline (510.991 us; speedup 1.0000x reference)
//
#include <hip/hip_runtime.h>
#include <hip/hip_bf16.h>

// Problem: B=2, H=8, S=2048, D=64, fp32 in/out.
// out = concat(attention [B,H,S,S], sum_value [B,H,S,D]) fp32.
#define SS 2048
#define DD 64
#define HH 8
#define NB 2

typedef __bf16 bf16x8 __attribute__((ext_vector_type(8)));
typedef float f32x4 __attribute__((ext_vector_type(4)));

__device__ __forceinline__ unsigned short f2bf(float f) {
  unsigned int u = __float_as_uint(f);
  u += 0x7fff + ((u >> 16) & 1);   // RNE
  return (unsigned short)(u >> 16);
}

union U8 { ushort4 u[2]; bf16x8 v; };

__device__ __forceinline__ bf16x8 ld8(const ushort* p) {
  U8 t;
  t.u[0] = *(const ushort4*)p;
  t.u[1] = *(const ushort4*)(p + 4);
  return t.v;
}

// Block: 256 threads = 4 waves; each block: one (b,h), 64 queries (16/wave).
// Per key-tile of 64: QK^T via 8x mfma_f32_16x16x32_bf16, PV via 8 more.
// LDS rows padded to 72 ushorts (144 B): 8B-aligned b64 frag reads, bank-start
// 4*row%32 -> <=2-way conflicts (free per m136).
__global__ __launch_bounds__(256) void attn_kernel(
    const float* __restrict__ Q, const float* __restrict__ K,
    const float* __restrict__ V, const int* __restrict__ maskp,
    float* __restrict__ attn, float* __restrict__ sv) {
  __shared__ ushort Kb[64][72];
  __shared__ ushort Vt[64][72];       // V transposed: Vt[d][key]
  __shared__ ushort Pb[4][16][72];    // per-wave normalized P (bf16)

  const int tid = threadIdx.x;
  const int lane = tid & 63;
  const int w = tid >> 6;
  const int col = lane & 15;          // MFMA col / A-row index
  const int g = lane >> 4;            // lane quarter
  const int bh = blockIdx.y;
  const int b = bh >> 3;
  const int q0 = blockIdx.x * 64;

  const size_t bhSD = (size_t)bh * SS * DD;

  // ---- Q fragments (A-operand) held in registers for both passes ----
  // A layout: lane holds row=lane&15, k = (lane>>4)*8 + i  (k-chunk s of 32)
  bf16x8 aq[2];
  {
    const int qg = q0 + w * 16 + col;
    const float* qrow = Q + bhSD + (size_t)qg * DD;
    #pragma unroll
    for (int s = 0; s < 2; ++s) {
      const float4* qp = (const float4*)(qrow + s * 32 + g * 8);
      float4 f0 = qp[0], f1 = qp[1];
      U8 t;
      t.u[0] = make_ushort4(f2bf(f0.x), f2bf(f0.y), f2bf(f0.z), f2bf(f0.w));
      t.u[1] = make_ushort4(f2bf(f1.x), f2bf(f1.y), f2bf(f1.z), f2bf(f1.w));
      aq[s] = t.v;
    }
  }

  // =============== Pass A: row sums l[q] = sum_k exp(s) ===============
  float lacc[4] = {0.f, 0.f, 0.f, 0.f};
  for (int kt = 0; kt < 32; ++kt) {
    __syncthreads();
    const float4* ksrc = (const float4*)(K + bhSD + (size_t)kt * 64 * DD);
    #pragma unroll
    for (int i = 0; i < 4; ++i) {
      int f = tid + 256 * i;
      float4 v = ksrc[f];
      int row = f >> 4, c4 = f & 15;
      *(ushort4*)&Kb[row][c4 * 4] =
          make_ushort4(f2bf(v.x), f2bf(v.y), f2bf(v.z), f2bf(v.w));
    }
    __syncthreads();

    f32x4 acc[4] = {};
    #pragma unroll
    for (int s = 0; s < 2; ++s) {
      #pragma unroll
      for (int c = 0; c < 4; ++c) {
        bf16x8 bk = ld8(&Kb[c * 16 + col][s * 32 + g * 8]);
        acc[c] = __builtin_amdgcn_mfma_f32_16x16x32_bf16(aq[s], bk, acc[c], 0, 0, 0);
      }
    }
    int m4[4];
    #pragma unroll
    for (int c = 0; c < 4; ++c)
      m4[c] = maskp[b * SS + kt * 64 + c * 16 + col];
    #pragma unroll
    for (int c = 0; c < 4; ++c) {
      int key = kt * 64 + c * 16 + col;
      #pragma unroll
      for (int r = 0; r < 4; ++r) {
        int qg = q0 + w * 16 + g * 4 + r;
        float p = (m4[c] != 0 || key == qg) ? 0.f : __expf(acc[c][r] * 0.125f);
        lacc[r] += p;
      }
    }
  }
  float inv_l[4];
  #pragma unroll
  for (int r = 0; r < 4; ++r) {
    float t = lacc[r];
    t += __shfl_xor(t, 1);
    t += __shfl_xor(t, 2);
    t += __shfl_xor(t, 4);
    t += __shfl_xor(t, 8);
    inv_l[r] = 1.0f / t;
  }

  // ====== Pass B: recompute scores, write attention, accumulate PV ======
  f32x4 oacc[4] = {};
  for (int kt = 0; kt < 32; ++kt) {
    __syncthreads();
    const float4* ksrc = (const float4*)(K + bhSD + (size_t)kt * 64 * DD);
    const float4* vsrc = (const float4*)(V + bhSD + (size_t)kt * 64 * DD);
    #pragma unroll
    for (int i = 0; i < 4; ++i) {
      int f = tid + 256 * i;
      float4 v = ksrc[f];
      int row = f >> 4, c4 = f & 15;
      *(ushort4*)&Kb[row][c4 * 4] =
          make_ushort4(f2bf(v.x), f2bf(v.y), f2bf(v.z), f2bf(v.w));
      float4 vv = vsrc[f];
      int d0 = c4 * 4;
      Vt[d0 + 0][row] = f2bf(vv.x);
      Vt[d0 + 1][row] = f2bf(vv.y);
      Vt[d0 + 2][row] = f2bf(vv.z);
      Vt[d0 + 3][row] = f2bf(vv.w);
    }
    __syncthreads();

    f32x4 acc[4] = {};
    #pragma unroll
    for (int s = 0; s < 2; ++s) {
      #pragma unroll
      for (int c = 0; c < 4; ++c) {
        bf16x8 bk = ld8(&Kb[c * 16 + col][s * 32 + g * 8]);
        acc[c] = __builtin_amdgcn_mfma_f32_16x16x32_bf16(aq[s], bk, acc[c], 0, 0, 0);
      }
    }
    int m4[4];
    #pragma unroll
    for (int c = 0; c < 4; ++c)
      m4[c] = maskp[b * SS + kt * 64 + c * 16 + col];
    #pragma unroll
    for (int c = 0; c < 4; ++c) {
      int key = kt * 64 + c * 16 + col;
      #pragma unroll
      for (int r = 0; r < 4; ++r) {
        int qg = q0 + w * 16 + g * 4 + r;
        float p = (m4[c] != 0 || key == qg) ? 0.f : __expf(acc[c][r] * 0.125f);
        float pn = p * inv_l[r];
        attn[((size_t)(bh * SS) + qg) * SS + key] = pn;
        Pb[w][g * 4 + r][c * 16 + col] = f2bf(pn);
      }
    }
    // PV: A = P (from Pb, wave-private), B = V^T (from Vt)
    #pragma unroll
    for (int s = 0; s < 2; ++s) {
      bf16x8 ap = ld8(&Pb[w][col][s * 32 + g * 8]);
      #pragma unroll
      for (int c2 = 0; c2 < 4; ++c2) {
        bf16x8 bv = ld8(&Vt[c2 * 16 + col][s * 32 + g * 8]);
        oacc[c2] = __builtin_amdgcn_mfma_f32_16x16x32_bf16(ap, bv, oacc[c2], 0, 0, 0);
      }
    }
  }

  // ---- store sum_value ----
  #pragma unroll
  for (int c2 = 0; c2 < 4; ++c2) {
    #pragma unroll
    for (int r = 0; r < 4; ++r) {
      int qg = q0 + w * 16 + g * 4 + r;
      sv[((size_t)(bh * SS) + qg) * DD + c2 * 16 + col] = oacc[c2][r];
    }
  }
}

extern "C" void kernel_launch(void* const* d_in, const int* in_sizes, int n_in,
                              void* d_out, int out_size, void* d_ws, size_t ws_size,
                              hipStream_t stream) {
  const float* Q = (const float*)d_in[0];
  const float* K = (const float*)d_in[1];
  const float* V = (const float*)d_in[2];
  const int* mask = (const int*)d_in[3];
  float* out = (float*)d_out;
  float* attn = out;                                   // B*H*S*S
  float* sv = out + (size_t)NB * HH * SS * SS;         // B*H*S*D
  dim3 grid(SS / 64, NB * HH);
  attn_kernel<<<grid, 256, 0, stream>>>(Q, K, V, mask, attn, sv);
}

// Round 2
// 412.242 us; speedup vs baseline: 1.2395x; 1.2395x over previous
//
#include <hip/hip_runtime.h>
#include <hip/hip_bf16.h>

// B=2, H=8, S=2048, D=64, fp32 in/out.
// out = concat(attention [B,H,S,S], sum_value [B,H,S,D]) fp32.
#define SS 2048
#define DD 64
#define HH 8
#define NB 2

typedef __bf16 bf16x8 __attribute__((ext_vector_type(8)));
typedef float f32x4 __attribute__((ext_vector_type(4)));

__device__ __forceinline__ unsigned short f2bf(float f) {
  unsigned int u = __float_as_uint(f);
  u += 0x7fff + ((u >> 16) & 1);   // RNE
  return (unsigned short)(u >> 16);
}

union U8 { ushort4 u[2]; bf16x8 v; };

__device__ __forceinline__ bf16x8 ld8(const ushort* p) {
  U8 t;
  t.u[0] = *(const ushort4*)p;
  t.u[1] = *(const ushort4*)(p + 4);
  return t.v;
}

// 512 threads = 8 waves = 2 key-groups x 4 waves. Each block: one (b,h),
// 64 queries; group g handles keys [g*1024, g*1024+1024).
// Pass A: group-partial row sums -> combine via LDS.
// Pass B: recompute scores, stage normalized fp32 P in LDS, coalesced float4
// attention writes, PV partial per group -> combine via LDS.
__global__ __launch_bounds__(512) void attn_kernel(
    const float* __restrict__ Q, const float* __restrict__ K,
    const float* __restrict__ V, const int* __restrict__ maskp,
    float* __restrict__ attn, float* __restrict__ sv) {
  __shared__ ushort Kb[2][64][72];   // K tile per group (row-major, keys x d)
  __shared__ ushort Vt[2][64][68];   // V^T per group: Vt[d][key]
  __shared__ float Pf[2][64][68];    // normalized P fp32 per group (q x key)
  __shared__ float Lred[8][16];      // per-wave row sums

  const int tid = threadIdx.x;
  const int lane = tid & 63;
  const int w = tid >> 6;        // wave 0..7
  const int grp = w >> 2;        // key-group 0/1
  const int wl = w & 3;          // wave within group -> query slab
  const int t2 = tid & 255;      // thread within group
  const int col = lane & 15;
  const int g = lane >> 4;
  const int bh = blockIdx.y;
  const int b = bh >> 3;
  const int q0 = blockIdx.x * 64;
  const int kbase = grp * 1024;

  const size_t bhSD = (size_t)bh * SS * DD;

  // ---- Q fragments (A-operand), rows q0 + wl*16 + col ----
  bf16x8 aq[2];
  {
    const float* qrow = Q + bhSD + (size_t)(q0 + wl * 16 + col) * DD;
    #pragma unroll
    for (int s = 0; s < 2; ++s) {
      const float4* qp = (const float4*)(qrow + s * 32 + g * 8);
      float4 f0 = qp[0], f1 = qp[1];
      U8 t;
      t.u[0] = make_ushort4(f2bf(f0.x), f2bf(f0.y), f2bf(f0.z), f2bf(f0.w));
      t.u[1] = make_ushort4(f2bf(f1.x), f2bf(f1.y), f2bf(f1.z), f2bf(f1.w));
      aq[s] = t.v;
    }
  }

  // =============== Pass A: partial row sums over this group's keys ========
  float lacc[4] = {0.f, 0.f, 0.f, 0.f};
  for (int kt = 0; kt < 16; ++kt) {
    __syncthreads();
    const float4* ksrc = (const float4*)(K + bhSD + (size_t)(kbase + kt * 64) * DD);
    #pragma unroll
    for (int i = 0; i < 4; ++i) {
      int f = t2 + 256 * i;
      float4 v = ksrc[f];
      int row = f >> 4, c4 = f & 15;
      *(ushort4*)&Kb[grp][row][c4 * 4] =
          make_ushort4(f2bf(v.x), f2bf(v.y), f2bf(v.z), f2bf(v.w));
    }
    __syncthreads();

    f32x4 acc[4] = {};
    #pragma unroll
    for (int s = 0; s < 2; ++s) {
      #pragma unroll
      for (int c = 0; c < 4; ++c) {
        bf16x8 bk = ld8(&Kb[grp][c * 16 + col][s * 32 + g * 8]);
        acc[c] = __builtin_amdgcn_mfma_f32_16x16x32_bf16(aq[s], bk, acc[c], 0, 0, 0);
      }
    }
    int m4[4];
    #pragma unroll
    for (int c = 0; c < 4; ++c)
      m4[c] = maskp[b * SS + kbase + kt * 64 + c * 16 + col];
    #pragma unroll
    for (int c = 0; c < 4; ++c) {
      int key = kbase + kt * 64 + c * 16 + col;
      #pragma unroll
      for (int r = 0; r < 4; ++r) {
        int qg = q0 + wl * 16 + g * 4 + r;
        float p = (m4[c] != 0 || key == qg) ? 0.f : __expf(acc[c][r] * 0.125f);
        lacc[r] += p;
      }
    }
  }
  // reduce over the 16 cols within each lane-quarter, publish per-wave
  #pragma unroll
  for (int r = 0; r < 4; ++r) {
    float t = lacc[r];
    t += __shfl_xor(t, 1);
    t += __shfl_xor(t, 2);
    t += __shfl_xor(t, 4);
    t += __shfl_xor(t, 8);
    if (col == 0) Lred[w][g * 4 + r] = t;
  }
  __syncthreads();
  float inv_l[4];
  #pragma unroll
  for (int r = 0; r < 4; ++r)
    inv_l[r] = 1.0f / (Lred[wl][g * 4 + r] + Lred[4 + wl][g * 4 + r]);

  // ====== Pass B: recompute, write attention (coalesced), partial PV ======
  f32x4 oacc[4] = {};
  for (int kt = 0; kt < 16; ++kt) {
    __syncthreads();
    const float4* ksrc = (const float4*)(K + bhSD + (size_t)(kbase + kt * 64) * DD);
    const float4* vsrc = (const float4*)(V + bhSD + (size_t)(kbase + kt * 64) * DD);
    #pragma unroll
    for (int i = 0; i < 4; ++i) {
      int f = t2 + 256 * i;
      float4 v = ksrc[f];
      int row = f >> 4, c4 = f & 15;
      *(ushort4*)&Kb[grp][row][c4 * 4] =
          make_ushort4(f2bf(v.x), f2bf(v.y), f2bf(v.z), f2bf(v.w));
      float4 vv = vsrc[f];
      int d0 = c4 * 4;
      Vt[grp][d0 + 0][row] = f2bf(vv.x);
      Vt[grp][d0 + 1][row] = f2bf(vv.y);
      Vt[grp][d0 + 2][row] = f2bf(vv.z);
      Vt[grp][d0 + 3][row] = f2bf(vv.w);
    }
    __syncthreads();

    f32x4 acc[4] = {};
    #pragma unroll
    for (int s = 0; s < 2; ++s) {
      #pragma unroll
      for (int c = 0; c < 4; ++c) {
        bf16x8 bk = ld8(&Kb[grp][c * 16 + col][s * 32 + g * 8]);
        acc[c] = __builtin_amdgcn_mfma_f32_16x16x32_bf16(aq[s], bk, acc[c], 0, 0, 0);
      }
    }
    int m4[4];
    #pragma unroll
    for (int c = 0; c < 4; ++c)
      m4[c] = maskp[b * SS + kbase + kt * 64 + c * 16 + col];
    #pragma unroll
    for (int c = 0; c < 4; ++c) {
      int key = kbase + kt * 64 + c * 16 + col;
      #pragma unroll
      for (int r = 0; r < 4; ++r) {
        int qg = q0 + wl * 16 + g * 4 + r;
        float p = (m4[c] != 0 || key == qg) ? 0.f : __expf(acc[c][r] * 0.125f);
        Pf[grp][wl * 16 + g * 4 + r][c * 16 + col] = p * inv_l[r];
      }
    }
    __syncthreads();

    // coalesced attention writes from Pf (this group's 64q x 64k fp32 tile)
    {
      float* abase = attn + ((size_t)bh * SS + q0) * SS + (kbase + kt * 64);
      #pragma unroll
      for (int i = 0; i < 4; ++i) {
        int f4 = t2 + 256 * i;         // 0..1023
        int row = f4 >> 4;             // 0..63
        int cof = (f4 & 15) * 4;       // 0..60
        float4 val = *(const float4*)&Pf[grp][row][cof];
        *(float4*)&abase[(size_t)row * SS + cof] = val;
      }
    }

    // PV: A = P rows (from Pf, cvt to bf16), B = V^T
    #pragma unroll
    for (int s = 0; s < 2; ++s) {
      float4 p0 = *(const float4*)&Pf[grp][wl * 16 + col][s * 32 + g * 8];
      float4 p1 = *(const float4*)&Pf[grp][wl * 16 + col][s * 32 + g * 8 + 4];
      U8 t;
      t.u[0] = make_ushort4(f2bf(p0.x), f2bf(p0.y), f2bf(p0.z), f2bf(p0.w));
      t.u[1] = make_ushort4(f2bf(p1.x), f2bf(p1.y), f2bf(p1.z), f2bf(p1.w));
      bf16x8 ap = t.v;
      #pragma unroll
      for (int c2 = 0; c2 < 4; ++c2) {
        bf16x8 bv = ld8(&Vt[grp][c2 * 16 + col][s * 32 + g * 8]);
        oacc[c2] = __builtin_amdgcn_mfma_f32_16x16x32_bf16(ap, bv, oacc[c2], 0, 0, 0);
      }
    }
  }

  // ---- combine PV partials across groups, store sum_value ----
  __syncthreads();
  if (grp == 1) {
    #pragma unroll
    for (int c2 = 0; c2 < 4; ++c2)
      #pragma unroll
      for (int r = 0; r < 4; ++r)
        Pf[1][wl * 16 + g * 4 + r][c2 * 16 + col] = oacc[c2][r];
  }
  __syncthreads();
  if (grp == 0) {
    #pragma unroll
    for (int c2 = 0; c2 < 4; ++c2) {
      #pragma unroll
      for (int r = 0; r < 4; ++r) {
        int qg = q0 + wl * 16 + g * 4 + r;
        float s = oacc[c2][r] + Pf[1][wl * 16 + g * 4 + r][c2 * 16 + col];
        sv[((size_t)bh * SS + qg) * DD + c2 * 16 + col] = s;
      }
    }
  }
}

extern "C" void kernel_launch(void* const* d_in, const int* in_sizes, int n_in,
                              void* d_out, int out_size, void* d_ws, size_t ws_size,
                              hipStream_t stream) {
  const float* Q = (const float*)d_in[0];
  const float* K = (const float*)d_in[1];
  const float* V = (const float*)d_in[2];
  const int* mask = (const int*)d_in[3];
  float* out = (float*)d_out;
  float* attn = out;                                   // B*H*S*S
  float* sv = out + (size_t)NB * HH * SS * SS;         // B*H*S*D
  dim3 grid(SS / 64, NB * HH);
  attn_kernel<<<grid, 512, 0, stream>>>(Q, K, V, mask, attn, sv);
}

// Round 3
// 385.762 us; speedup vs baseline: 1.3246x; 1.0686x over previous
//
#include <hip/hip_runtime.h>
#include <hip/hip_bf16.h>

// B=2, H=8, S=2048, D=64, fp32 in/out.
// out = concat(attention [B,H,S,S], sum_value [B,H,S,D]) fp32.
#define SS 2048
#define DD 64
#define HH 8
#define NB 2
#define NT 8            // key tiles per block
#define KEYS_PER 512    // keys per block (k-split 4)

typedef __bf16 bf16x8 __attribute__((ext_vector_type(8)));
typedef float f32x4 __attribute__((ext_vector_type(4)));

__device__ __forceinline__ unsigned short f2bf(float f) {
  unsigned int u = __float_as_uint(f);
  u += 0x7fff + ((u >> 16) & 1);   // RNE
  return (unsigned short)(u >> 16);
}
__device__ __forceinline__ unsigned int cvtpk(float lo, float hi) {
  unsigned int r;
  asm("v_cvt_pk_bf16_f32 %0, %1, %2" : "=v"(r) : "v"(lo), "v"(hi));
  return r;
}
union U8 { ushort4 u[2]; bf16x8 v; };
union UW { uint4 w; bf16x8 v; };
__device__ __forceinline__ bf16x8 ld8(const ushort* p) {
  U8 t;
  t.u[0] = *(const ushort4*)p;
  t.u[1] = *(const ushort4*)(p + 4);
  return t.v;
}
// XCD-bijective swizzle: 2048 blocks, 8 XCDs; same-(kg,bh) q-tiles land on
// one XCD for K/V L2 reuse.
__device__ __forceinline__ void decode(int& qt, int& kg, int& bh) {
  int lin = blockIdx.x + 32 * (blockIdx.y + 4 * blockIdx.z);
  int wid = (lin & 7) * 256 + (lin >> 3);
  qt = wid & 31; kg = (wid >> 5) & 3; bh = wid >> 7;
}

// ============ Kernel 1: partial row sums l_part[kg][bh][q] ============
__global__ __launch_bounds__(256, 4) void sums_kernel(
    const float* __restrict__ Q, const float* __restrict__ K,
    const int* __restrict__ maskp, float* __restrict__ lpart) {
  __shared__ ushort Kb[64][68];
  __shared__ unsigned long long Mb[NT];
  int qt, kg, bh; decode(qt, kg, bh);
  const int tid = threadIdx.x, lane = tid & 63, w = tid >> 6;
  const int col = lane & 15, g = lane >> 4;
  const int q0 = qt * 64, kb0 = kg * KEYS_PER, b = bh >> 3;
  const size_t bhSD = (size_t)bh * SS * DD;

  // mask -> bitmask (8 x 64-bit words)
  {
    unsigned long long b0 = __ballot(maskp[b * SS + kb0 + (2 * w) * 64 + lane] != 0);
    unsigned long long b1 = __ballot(maskp[b * SS + kb0 + (2 * w + 1) * 64 + lane] != 0);
    if (lane == 0) { Mb[2 * w] = b0; Mb[2 * w + 1] = b1; }
  }

  // Q fragments (A-operand): row = q0 + w*16 + col
  bf16x8 aq[2];
  {
    const float* qrow = Q + bhSD + (size_t)(q0 + w * 16 + col) * DD;
    #pragma unroll
    for (int s = 0; s < 2; ++s) {
      const float4* qp = (const float4*)(qrow + s * 32 + g * 8);
      float4 f0 = qp[0], f1 = qp[1];
      UW t;
      t.w = make_uint4(cvtpk(f0.x, f0.y), cvtpk(f0.z, f0.w),
                       cvtpk(f1.x, f1.y), cvtpk(f1.z, f1.w));
      aq[s] = t.v;
    }
  }

  // prologue prefetch
  float4 kreg[4];
  {
    const float4* ks = (const float4*)(K + bhSD + (size_t)kb0 * DD);
    #pragma unroll
    for (int i = 0; i < 4; ++i) kreg[i] = ks[tid + 256 * i];
  }

  float lacc[4] = {0.f, 0.f, 0.f, 0.f};
  for (int kt = 0; kt < NT; ++kt) {
    __syncthreads();
    #pragma unroll
    for (int i = 0; i < 4; ++i) {
      int f = tid + 256 * i, row = f >> 4, c4 = f & 15;
      float4 v = kreg[i];
      *(uint2*)&Kb[row][c4 * 4] = make_uint2(cvtpk(v.x, v.y), cvtpk(v.z, v.w));
    }
    __syncthreads();
    if (kt + 1 < NT) {
      const float4* ks = (const float4*)(K + bhSD + (size_t)(kb0 + (kt + 1) * 64) * DD);
      #pragma unroll
      for (int i = 0; i < 4; ++i) kreg[i] = ks[tid + 256 * i];
    }
    f32x4 acc[4] = {};
    #pragma unroll
    for (int s = 0; s < 2; ++s) {
      #pragma unroll
      for (int c = 0; c < 4; ++c) {
        bf16x8 bk = ld8(&Kb[c * 16 + col][s * 32 + g * 8]);
        acc[c] = __builtin_amdgcn_mfma_f32_16x16x32_bf16(aq[s], bk, acc[c], 0, 0, 0);
      }
    }
    unsigned long long mw = Mb[kt];
    #pragma unroll
    for (int c = 0; c < 4; ++c) {
      unsigned int slice = (unsigned int)(mw >> (c * 16)) & 0xFFFFu;
      int mbit = (slice >> col) & 1;
      int key = kb0 + kt * 64 + c * 16 + col;
      #pragma unroll
      for (int r = 0; r < 4; ++r) {
        int qg = q0 + w * 16 + g * 4 + r;
        float p = (mbit || key == qg) ? 0.f : exp2f(acc[c][r] * 0.18033688011112042f);
        lacc[r] += p;
      }
    }
  }
  #pragma unroll
  for (int r = 0; r < 4; ++r) {
    float t = lacc[r];
    t += __shfl_xor(t, 1);
    t += __shfl_xor(t, 2);
    t += __shfl_xor(t, 4);
    t += __shfl_xor(t, 8);
    if (col == 0)
      lpart[((kg * 16 + bh) << 11) + q0 + w * 16 + g * 4 + r] = t;
  }
}

// ============ Kernel 2: emit attention + PV partials ============
__global__ __launch_bounds__(256, 4) void emit_kernel(
    const float* __restrict__ Q, const float* __restrict__ K,
    const float* __restrict__ V, const int* __restrict__ maskp,
    const float* __restrict__ lpart, float* __restrict__ attn,
    float* __restrict__ sv) {
  __shared__ ushort Kb[64][68];
  __shared__ ushort Vt[64][68];      // V^T: Vt[d][key]
  __shared__ ushort Pb[4][16][68];   // per-wave P tile (bf16), wave-private
  __shared__ unsigned long long Mb[NT];
  int qt, kg, bh; decode(qt, kg, bh);
  const int tid = threadIdx.x, lane = tid & 63, w = tid >> 6;
  const int col = lane & 15, g = lane >> 4;
  const int q0 = qt * 64, kb0 = kg * KEYS_PER, b = bh >> 3;
  const size_t bhSD = (size_t)bh * SS * DD;

  {
    unsigned long long b0 = __ballot(maskp[b * SS + kb0 + (2 * w) * 64 + lane] != 0);
    unsigned long long b1 = __ballot(maskp[b * SS + kb0 + (2 * w + 1) * 64 + lane] != 0);
    if (lane == 0) { Mb[2 * w] = b0; Mb[2 * w + 1] = b1; }
  }

  bf16x8 aq[2];
  {
    const float* qrow = Q + bhSD + (size_t)(q0 + w * 16 + col) * DD;
    #pragma unroll
    for (int s = 0; s < 2; ++s) {
      const float4* qp = (const float4*)(qrow + s * 32 + g * 8);
      float4 f0 = qp[0], f1 = qp[1];
      UW t;
      t.w = make_uint4(cvtpk(f0.x, f0.y), cvtpk(f0.z, f0.w),
                       cvtpk(f1.x, f1.y), cvtpk(f1.z, f1.w));
      aq[s] = t.v;
    }
  }

  // 1/l per row (sum the 4 k-group partials)
  float inv_l[4];
  #pragma unroll
  for (int r = 0; r < 4; ++r) {
    int qg = q0 + w * 16 + g * 4 + r;
    float s = 0.f;
    #pragma unroll
    for (int kk = 0; kk < 4; ++kk) s += lpart[((kk * 16 + bh) << 11) + qg];
    inv_l[r] = 1.0f / s;
  }

  // per-row attn base pointers
  float* arow[4];
  #pragma unroll
  for (int r = 0; r < 4; ++r)
    arow[r] = attn + ((size_t)bh * SS + q0 + w * 16 + g * 4 + r) * SS + kb0;

  // prologue prefetch K+V
  float4 kreg[4], vreg[4];
  {
    const float4* ks = (const float4*)(K + bhSD + (size_t)kb0 * DD);
    const float4* vs = (const float4*)(V + bhSD + (size_t)kb0 * DD);
    #pragma unroll
    for (int i = 0; i < 4; ++i) { kreg[i] = ks[tid + 256 * i]; vreg[i] = vs[tid + 256 * i]; }
  }

  f32x4 oacc[4] = {};
  for (int kt = 0; kt < NT; ++kt) {
    __syncthreads();
    #pragma unroll
    for (int i = 0; i < 4; ++i) {
      int f = tid + 256 * i, row = f >> 4, c4 = f & 15;
      float4 kv = kreg[i];
      *(uint2*)&Kb[row][c4 * 4] = make_uint2(cvtpk(kv.x, kv.y), cvtpk(kv.z, kv.w));
      float4 vv = vreg[i];
      int d0 = c4 * 4;
      Vt[d0 + 0][row] = f2bf(vv.x);
      Vt[d0 + 1][row] = f2bf(vv.y);
      Vt[d0 + 2][row] = f2bf(vv.z);
      Vt[d0 + 3][row] = f2bf(vv.w);
    }
    __syncthreads();
    if (kt + 1 < NT) {   // prefetch next tile during compute
      const float4* ks = (const float4*)(K + bhSD + (size_t)(kb0 + (kt + 1) * 64) * DD);
      const float4* vs = (const float4*)(V + bhSD + (size_t)(kb0 + (kt + 1) * 64) * DD);
      #pragma unroll
      for (int i = 0; i < 4; ++i) { kreg[i] = ks[tid + 256 * i]; vreg[i] = vs[tid + 256 * i]; }
    }

    f32x4 acc[4] = {};
    #pragma unroll
    for (int s = 0; s < 2; ++s) {
      #pragma unroll
      for (int c = 0; c < 4; ++c) {
        bf16x8 bk = ld8(&Kb[c * 16 + col][s * 32 + g * 8]);
        acc[c] = __builtin_amdgcn_mfma_f32_16x16x32_bf16(aq[s], bk, acc[c], 0, 0, 0);
      }
    }
    unsigned long long mw = Mb[kt];
    #pragma unroll
    for (int c = 0; c < 4; ++c) {
      unsigned int slice = (unsigned int)(mw >> (c * 16)) & 0xFFFFu;
      int mbit = (slice >> col) & 1;
      int key = kb0 + kt * 64 + c * 16 + col;
      #pragma unroll
      for (int r = 0; r < 4; ++r) {
        int qg = q0 + w * 16 + g * 4 + r;
        float p = (mbit || key == qg) ? 0.f : exp2f(acc[c][r] * 0.18033688011112042f);
        float pn = p * inv_l[r];
        arow[r][kt * 64 + c * 16 + col] = pn;            // direct attn store
        Pb[w][g * 4 + r][c * 16 + col] = f2bf(pn);       // wave-private, no barrier
      }
    }
    // PV: A = P rows, B = V^T
    #pragma unroll
    for (int s = 0; s < 2; ++s) {
      bf16x8 ap = ld8(&Pb[w][col][s * 32 + g * 8]);
      #pragma unroll
      for (int c2 = 0; c2 < 4; ++c2) {
        bf16x8 bv = ld8(&Vt[c2 * 16 + col][s * 32 + g * 8]);
        oacc[c2] = __builtin_amdgcn_mfma_f32_16x16x32_bf16(ap, bv, oacc[c2], 0, 0, 0);
      }
    }
  }

  // PV partial combine across the 4 k-groups
  #pragma unroll
  for (int c2 = 0; c2 < 4; ++c2) {
    #pragma unroll
    for (int r = 0; r < 4; ++r) {
      int qg = q0 + w * 16 + g * 4 + r;
      atomicAdd(&sv[((size_t)bh * SS + qg) * DD + c2 * 16 + col], oacc[c2][r]);
    }
  }
}

extern "C" void kernel_launch(void* const* d_in, const int* in_sizes, int n_in,
                              void* d_out, int out_size, void* d_ws, size_t ws_size,
                              hipStream_t stream) {
  const float* Q = (const float*)d_in[0];
  const float* K = (const float*)d_in[1];
  const float* V = (const float*)d_in[2];
  const int* mask = (const int*)d_in[3];
  float* out = (float*)d_out;
  float* attn = out;                                   // B*H*S*S
  float* sv = out + (size_t)NB * HH * SS * SS;         // B*H*S*D
  float* lpart = (float*)d_ws;                         // [4][16][2048] fp32

  hipMemsetAsync(sv, 0, (size_t)NB * HH * SS * DD * sizeof(float), stream);
  dim3 grid(SS / 64, 4, NB * HH);
  sums_kernel<<<grid, 256, 0, stream>>>(Q, K, mask, lpart);
  emit_kernel<<<grid, 256, 0, stream>>>(Q, K, V, mask, lpart, attn, sv);
}